// Round 11
// baseline (80.739 us; speedup 1.0000x reference)
//
#include <hip/hip_runtime.h>

// Discrete color pick via fp32 sign tests: predicates must match numpy fp32
// rounding bit-exactly. contract(off) keeps every exact path exact (tri edge
// functions and circle MUST stay mul,mul,sub/add - no fma fusion).
//
// r11: binding pipe is LDS instruction throughput (b128~12cyc, b32~5.8cyc per
// wave-instr per CU; r10's -12% DS-weight gave -8% kernel). Two instr-count
// trims: (1) color gather moved to global p (VMEM pipe idle, L1-resident;
// -1 ds_read_b128/point, no color staging); (2) 1024 persistent-ish blocks x
// 4 grid-stride chunks amortize LDS staging + barrier and cut launch count.
// Payload stays at the 13-float minimum (3xb128 + 1xb32 per visit).
#pragma clang fp contract(off)

#define NPTS 2097152
#define PPT  2
#define NTHREADS (NPTS / PPT)   // 1048576
#define CHUNKS 4
#define NBLOCKS (NTHREADS / 256 / CHUNKS)   // 1024

// LDS float layout (padded 7x7 grid, row-major ci = 7*gi+gj):
//   L_A [49][4]: ax,ay,bx,by      (floats 0..195)
//   L_B [49][4]: cx,cy,ocx,ocy    (floats 196..391)
//   L_C [49][4]: r,ecx,ecy,1/erx  (floats 392..587)
//   L_D [49][4]: 1/ery,pad,pad,pad(floats 588..783; read .x as b32)
#define L_B    196
#define L_C    392
#define L_D    588
#define LDS_FLOATS 784   // 3136 B

// Ellipse screen band (only remaining screen): recip-mul + fma-reassoc vs
// numpy div-mul-add |delta| <= ~6e-7 on te~1 -> 1e-5 (validated r1-r10,
// absmax 0.0 every round). Tri and circle are evaluated EXACTLY inline.
#define EPS_E 1e-5f

// Bit-exact numpy-order evaluation over the 4 candidate cells, reading raw
// params (fl(by-ay) etc. reproduce numpy's fp32 ops exactly). Non-candidate
// shapes are >= 5e-4 away geometrically vs fp sign-test reach ~3e-7, so the
// 4-cell restriction is exact for numpy arithmetic too. Rare (~1e-3 of pts,
// ellipse band only).
__device__ __noinline__ int exact_point(float px, float py, int ih, int jh,
                                        const float* __restrict__ p) {
    int idx = -1;
#pragma clang loop unroll(disable)
    for (int s = 0; s < 4; ++s) {
        int ii = ih - 1 + (s >> 1), jj = jh - 1 + (s & 1);   // ascending cell
        if ((unsigned)ii > 4u || (unsigned)jj > 4u) continue;
        int c = 5 * ii + jj;
        const float* cell = p + 28 * c;
        float ax = cell[1], ay = cell[2], bx = cell[3], by = cell[4], cx = cell[5], cy = cell[6];
        float e0 = (px - ax) * (by - ay) - (py - ay) * (bx - ax);
        float e1 = (px - bx) * (cy - by) - (py - by) * (cx - bx);
        float e2 = (px - cx) * (ay - cy) - (py - cy) * (ax - cx);
        bool tin = (e0 >= 0.f && e1 >= 0.f && e2 >= 0.f) ||
                   (e0 <= 0.f && e1 <= 0.f && e2 <= 0.f);
        if (tin) idx = 3 * c;
        float dx = px - cell[12], dy = py - cell[13];
        if (dx * dx + dy * dy <= cell[14] * cell[14]) idx = 3 * c + 1;
        float u = (px - cell[20]) / cell[22];   // IEEE division, numpy order
        float v = (py - cell[21]) / cell[23];
        if (u * u + v * v <= 1.0f) idx = 3 * c + 2;
    }
    return idx;
}

__global__ __launch_bounds__(256) void vg_fused(const float* __restrict__ x,
                                                const float* __restrict__ p,
                                                float* __restrict__ out) {
    __shared__ float lds[LDS_FLOATS];
    int tl = threadIdx.x;

    // ---- build padded SoA cell tables ONCE per block (threads 0..48) ----
    if (tl < 49) {
        int gi = tl / 7, gj = tl % 7;
        float4* A = (float4*)lds;
        float4* B = (float4*)(lds + L_B);
        float4* C = (float4*)(lds + L_C);
        float4* D = (float4*)(lds + L_D);
        if (gi >= 1 && gi <= 5 && gj >= 1 && gj <= 5) {
            int c = (gi - 1) * 5 + (gj - 1);
            const float* cell = p + c * 28;
            A[tl] = make_float4(cell[1], cell[2], cell[3], cell[4]);    // ax,ay,bx,by
            B[tl] = make_float4(cell[5], cell[6], cell[12], cell[13]);  // cx,cy,ocx,ocy
            C[tl] = make_float4(cell[14], cell[20], cell[21], 1.0f / cell[22]); // r,ecx,ecy,irx
            D[tl] = make_float4(1.0f / cell[23], 0.f, 0.f, 0.f);        // iry
        } else {
            // dummy border cell: tri edges strictly mixed-sign for any point
            // in [0,1]^2 (e0<=-2, e1>=+2); circle/ellipse centers far away.
            A[tl] = make_float4(0.f, -2.f, 1.f, -2.f);
            B[tl] = make_float4(0.f, -3.f, 50.f, 50.f);
            C[tl] = make_float4(0.f, 50.f, 50.f, 1.f);
            D[tl] = make_float4(1.f, 0.f, 0.f, 0.f);
        }
    }
    __syncthreads();

    const float4* LA = (const float4*)lds;
    const float4* LB = (const float4*)(lds + L_B);
    const float4* LC = (const float4*)(lds + L_C);
    const int coff[4] = {0, 1, 7, 8};
    const int soff[4] = {0, 3, 15, 18};

#pragma unroll 1
    for (int it = 0; it < CHUNKS; ++it) {
        int t = (blockIdx.x * CHUNKS + it) * 256 + tl;

        // ---- load 2 points (one contiguous float4 per lane, coalesced) ----
        float4 xv = ((const float4*)x)[t];
        float PX[PPT] = {xv.x, xv.z};
        float PY[PPT] = {xv.y, xv.w};
        int idx[PPT], ih[PPT], jh[PPT], sb[PPT], cb[PPT];
        bool unc[PPT];

#pragma unroll
        for (int k = 0; k < PPT; ++k) {
            // padded candidate block {ih,ih+1}x{jh,jh+1}; ih = floor(5X+0.4025)
            // in [0,5] (reach 0.0805 >= 0.08 shape reach + fp slack; r4-r10 proven)
            ih[k] = (int)floorf(__builtin_fmaf(PX[k], 5.0f, 0.4025f));
            jh[k] = (int)floorf(__builtin_fmaf(PY[k], 5.0f, 0.4025f));
            cb[k] = 7 * ih[k] + jh[k];           // ci = cb + {0,1,7,8}
            sb[k] = 15 * ih[k] + 3 * jh[k] - 18; // sid = sb + {0,3,15,18}
            idx[k] = -1; unc[k] = false;
        }

#pragma unroll
        for (int k = 0; k < PPT; ++k) {
            float X = PX[k], Y = PY[k];
#pragma unroll
            for (int s = 0; s < 4; ++s) {
                int ci = cb[k] + coff[s];
                // 3 b128 + 1 b32, one index, immediate offsets
                float4 A = LA[ci];
                float4 B = LB[ci];
                float4 C = LC[ci];
                float iry = lds[L_D + 4 * ci];
                int sid = sb[k] + soff[s];

                // ---- triangle: EXACT numpy fp32 (d's are the same fl() numpy
                // computes; mul,mul,sub under contract(off)) ----
                float d0y = A.w - A.y, d0x = A.z - A.x;   // by-ay, bx-ax
                float d1y = B.y - A.w, d1x = B.x - A.z;   // cy-by, cx-bx
                float d2y = A.y - B.y, d2x = A.x - B.x;   // ay-cy, ax-cx
                float e0 = (X - A.x) * d0y - (Y - A.y) * d0x;
                float e1 = (X - A.z) * d1y - (Y - A.w) * d1x;
                float e2 = (X - B.x) * d2y - (Y - B.y) * d2x;
                bool tin = (e0 >= 0.f && e1 >= 0.f && e2 >= 0.f) ||
                           (e0 <= 0.f && e1 <= 0.f && e2 <= 0.f);
                idx[k] = tin ? sid : idx[k];

                // ---- circle: EXACT numpy fp32 (r2 = fl(r*r); mul,mul,add) ----
                float r2 = C.x * C.x;
                float dx = X - B.z, dy = Y - B.w;
                float tc = dx * dx + dy * dy;
                idx[k] = (tc <= r2) ? sid + 1 : idx[k];

                // ---- ellipse: reciprocal screen + band -> bit-exact fallback ----
                float ex = X - C.y, ey = Y - C.z;
                float u = ex * C.w, v = ey * iry;
                float te = __builtin_fmaf(u, u, v * v);
                unc[k] = unc[k] | (__builtin_fabsf(te - 1.0f) < EPS_E);
                idx[k] = (te <= 1.0f) ? sid + 2 : idx[k];
            }
        }

        // rare bit-exact fallback (ellipse band only)
#pragma unroll
        for (int k = 0; k < PPT; ++k)
            if (__builtin_expect(unc[k], 0))
                idx[k] = exact_point(PX[k], PY[k], ih[k], jh[k], p);

        // ---- color gather from GLOBAL p (L1-resident 2.8KB; VMEM pipe idle;
        // copied values -> exact by construction). Branchless clamp+select. ----
        float col[PPT][3];
#pragma unroll
        for (int k = 0; k < PPT; ++k) {
            int id = idx[k] < 0 ? 0 : idx[k];
            int c = id / 3, kind = id - 3 * c;
            int off = 28 * c + (kind == 0 ? 8 : (kind == 1 ? 16 : 25));
            float r = p[off], g = p[off + 1], b = p[off + 2];
            bool none = idx[k] < 0;
            col[k][0] = none ? 0.f : r;
            col[k][1] = none ? 0.f : g;
            col[k][2] = none ? 0.f : b;
        }

        float2* o2 = (float2*)out;
        o2[3 * t + 0] = make_float2(col[0][0], col[0][1]);
        o2[3 * t + 1] = make_float2(col[0][2], col[1][0]);
        o2[3 * t + 2] = make_float2(col[1][1], col[1][2]);
    }
}

extern "C" void kernel_launch(void* const* d_in, const int* in_sizes, int n_in,
                              void* d_out, int out_size, void* d_ws, size_t ws_size,
                              hipStream_t stream) {
    const float* x = (const float*)d_in[0];   // (NPTS, 2) fp32
    const float* p = (const float*)d_in[1];   // (700,)   fp32
    float* out = (float*)d_out;               // (NPTS, 3) fp32
    (void)d_ws; (void)ws_size;

    vg_fused<<<NBLOCKS, 256, 0, stream>>>(x, p, out);
}

// Round 12
// 79.824 us; speedup vs baseline: 1.0115x; 1.0115x over previous
//
#include <hip/hip_runtime.h>

// Discrete color pick via fp32 sign tests: predicates must match numpy fp32
// rounding bit-exactly. contract(off) keeps every exact path exact (tri edge
// functions and circle MUST stay mul,mul,sub/add - no fma fusion).
//
// r12 = r10 revert (best: 78.83us total). Binding pipe is LDS gather
// instruction throughput: 13 floats/cell payload as 3xb128 + 1xb32, padded
// 7x7 grid, 4 candidate cells/point, exact tri+circle inline, ellipse via
// reciprocal screen + rare bit-exact fallback. r11's global-color +
// persistent-block variant regressed; r6/r8/r9 structural variants neutral.
#pragma clang fp contract(off)

#define NPTS 2097152
#define PPT  2
#define NTHREADS (NPTS / PPT)   // 1048576

// LDS float layout (padded 7x7 grid, row-major ci = 7*gi+gj):
//   L_A [49][4]: ax,ay,bx,by      (floats 0..195,   byte off 0)
//   L_B [49][4]: cx,cy,ocx,ocy    (floats 196..391, byte off  784)
//   L_C [49][4]: r,ecx,ecy,1/erx  (floats 392..587, byte off 1568)
//   L_D [49][4]: 1/ery,pad,pad,pad(floats 588..783, byte off 2352; read .x b32)
//   L_COL [76][4]: colors, entry 75 = black
#define L_B    196
#define L_C    392
#define L_D    588
#define L_COL  784
#define LDS_FLOATS (784 + 304)   // 4352 B

// Ellipse screen band (only remaining screen): recip-mul + fma-reassoc vs
// numpy div-mul-add |delta| <= ~6e-7 on te~1 -> 1e-5 (validated r1-r11,
// absmax 0.0 every round). Tri and circle are evaluated EXACTLY inline.
#define EPS_E 1e-5f

// Bit-exact numpy-order evaluation over the 4 candidate cells, reading raw
// params (fl(by-ay) etc. reproduce numpy's fp32 ops exactly). Non-candidate
// shapes are >= 5e-4 away geometrically vs fp sign-test reach ~3e-7, so the
// 4-cell restriction is exact for numpy arithmetic too. Rare (~1e-3 of pts,
// ellipse band only).
__device__ __noinline__ int exact_point(float px, float py, int ih, int jh,
                                        const float* __restrict__ p) {
    int idx = -1;
#pragma clang loop unroll(disable)
    for (int s = 0; s < 4; ++s) {
        int ii = ih - 1 + (s >> 1), jj = jh - 1 + (s & 1);   // ascending cell
        if ((unsigned)ii > 4u || (unsigned)jj > 4u) continue;
        int c = 5 * ii + jj;
        const float* cell = p + 28 * c;
        float ax = cell[1], ay = cell[2], bx = cell[3], by = cell[4], cx = cell[5], cy = cell[6];
        float e0 = (px - ax) * (by - ay) - (py - ay) * (bx - ax);
        float e1 = (px - bx) * (cy - by) - (py - by) * (cx - bx);
        float e2 = (px - cx) * (ay - cy) - (py - cy) * (ax - cx);
        bool tin = (e0 >= 0.f && e1 >= 0.f && e2 >= 0.f) ||
                   (e0 <= 0.f && e1 <= 0.f && e2 <= 0.f);
        if (tin) idx = 3 * c;
        float dx = px - cell[12], dy = py - cell[13];
        if (dx * dx + dy * dy <= cell[14] * cell[14]) idx = 3 * c + 1;
        float u = (px - cell[20]) / cell[22];   // IEEE division, numpy order
        float v = (py - cell[21]) / cell[23];
        if (u * u + v * v <= 1.0f) idx = 3 * c + 2;
    }
    return idx;
}

__global__ __launch_bounds__(256) void vg_fused(const float* __restrict__ x,
                                                const float* __restrict__ p,
                                                float* __restrict__ out) {
    __shared__ float lds[LDS_FLOATS];
    int tl = threadIdx.x;
    int t  = blockIdx.x * 256 + tl;

    // ---- build padded SoA cell tables (threads 0..48) ----
    if (tl < 49) {
        int gi = tl / 7, gj = tl % 7;
        float4* A = (float4*)lds;
        float4* B = (float4*)(lds + L_B);
        float4* C = (float4*)(lds + L_C);
        float4* D = (float4*)(lds + L_D);
        if (gi >= 1 && gi <= 5 && gj >= 1 && gj <= 5) {
            int c = (gi - 1) * 5 + (gj - 1);
            const float* cell = p + c * 28;
            A[tl] = make_float4(cell[1], cell[2], cell[3], cell[4]);    // ax,ay,bx,by
            B[tl] = make_float4(cell[5], cell[6], cell[12], cell[13]);  // cx,cy,ocx,ocy
            C[tl] = make_float4(cell[14], cell[20], cell[21], 1.0f / cell[22]); // r,ecx,ecy,irx
            D[tl] = make_float4(1.0f / cell[23], 0.f, 0.f, 0.f);        // iry
        } else {
            // dummy border cell: tri edges strictly mixed-sign for any point
            // in [0,1]^2 (e0<=-2, e1>=+2); circle/ellipse centers far away.
            A[tl] = make_float4(0.f, -2.f, 1.f, -2.f);
            B[tl] = make_float4(0.f, -3.f, 50.f, 50.f);
            C[tl] = make_float4(0.f, 50.f, 50.f, 1.f);
            D[tl] = make_float4(1.f, 0.f, 0.f, 0.f);
        }
    }
    // ---- build color table (threads 128..203 -> entries 0..75) ----
    if (tl >= 128 && tl < 204) {
        int e = tl - 128;
        float* col = lds + L_COL + e * 4;
        if (e < 75) {
            int c = e / 3, kind = e - 3 * c;
            const float* cell = p + c * 28;
            int base = (kind == 0) ? 8 : (kind == 1) ? 16 : 25;
            col[0] = cell[base]; col[1] = cell[base + 1]; col[2] = cell[base + 2];
        } else {
            col[0] = 0.f; col[1] = 0.f; col[2] = 0.f;   // no-hit -> black
        }
        col[3] = 0.f;
    }
    __syncthreads();

    // ---- load 2 points (one contiguous float4 per lane, coalesced) ----
    float4 xv = ((const float4*)x)[t];
    float PX[PPT] = {xv.x, xv.z};
    float PY[PPT] = {xv.y, xv.w};
    int idx[PPT], ih[PPT], jh[PPT], sb[PPT], cb[PPT];
    bool unc[PPT];

#pragma unroll
    for (int k = 0; k < PPT; ++k) {
        // padded candidate block {ih,ih+1}x{jh,jh+1}; ih = floor(5X+0.4025)
        // in [0,5] (reach 0.0805 >= 0.08 shape reach + fp slack; r4-r11 proven)
        ih[k] = (int)floorf(__builtin_fmaf(PX[k], 5.0f, 0.4025f));
        jh[k] = (int)floorf(__builtin_fmaf(PY[k], 5.0f, 0.4025f));
        cb[k] = 7 * ih[k] + jh[k];           // ci = cb + {0,1,7,8}
        sb[k] = 15 * ih[k] + 3 * jh[k] - 18; // sid = sb + {0,3,15,18}
        idx[k] = -1; unc[k] = false;
    }

    const float4* LA = (const float4*)lds;
    const float4* LB = (const float4*)(lds + L_B);
    const float4* LC = (const float4*)(lds + L_C);
    const int coff[4] = {0, 1, 7, 8};
    const int soff[4] = {0, 3, 15, 18};

#pragma unroll
    for (int k = 0; k < PPT; ++k) {
        float X = PX[k], Y = PY[k];
#pragma unroll
        for (int s = 0; s < 4; ++s) {
            int ci = cb[k] + coff[s];
            // 3 b128 + 1 b32, one index, immediate offsets 0/784/1568/2352
            float4 A = LA[ci];
            float4 B = LB[ci];
            float4 C = LC[ci];
            float iry = lds[L_D + 4 * ci];
            int sid = sb[k] + soff[s];

            // ---- triangle: EXACT numpy fp32 (d's are the same fl() numpy
            // computes; mul,mul,sub under contract(off)) ----
            float d0y = A.w - A.y, d0x = A.z - A.x;   // by-ay, bx-ax
            float d1y = B.y - A.w, d1x = B.x - A.z;   // cy-by, cx-bx
            float d2y = A.y - B.y, d2x = A.x - B.x;   // ay-cy, ax-cx
            float e0 = (X - A.x) * d0y - (Y - A.y) * d0x;
            float e1 = (X - A.z) * d1y - (Y - A.w) * d1x;
            float e2 = (X - B.x) * d2y - (Y - B.y) * d2x;
            bool tin = (e0 >= 0.f && e1 >= 0.f && e2 >= 0.f) ||
                       (e0 <= 0.f && e1 <= 0.f && e2 <= 0.f);
            idx[k] = tin ? sid : idx[k];

            // ---- circle: EXACT numpy fp32 (r2 = fl(r*r); mul,mul,add) ----
            float r2 = C.x * C.x;
            float dx = X - B.z, dy = Y - B.w;
            float tc = dx * dx + dy * dy;
            idx[k] = (tc <= r2) ? sid + 1 : idx[k];

            // ---- ellipse: reciprocal screen + band -> bit-exact fallback ----
            float ex = X - C.y, ey = Y - C.z;
            float u = ex * C.w, v = ey * iry;
            float te = __builtin_fmaf(u, u, v * v);
            unc[k] = unc[k] | (__builtin_fabsf(te - 1.0f) < EPS_E);
            idx[k] = (te <= 1.0f) ? sid + 2 : idx[k];
        }
    }

    // rare bit-exact fallback (ellipse band only)
#pragma unroll
    for (int k = 0; k < PPT; ++k)
        if (__builtin_expect(unc[k], 0))
            idx[k] = exact_point(PX[k], PY[k], ih[k], jh[k], p);

    // color gather from LDS (entry 75 = black) + coalesced 8B stores
    const float4* col4 = (const float4*)(lds + L_COL);
    float4 c0 = col4[idx[0] < 0 ? 75 : idx[0]];
    float4 c1 = col4[idx[1] < 0 ? 75 : idx[1]];

    float2* o2 = (float2*)out;
    o2[3 * t + 0] = make_float2(c0.x, c0.y);
    o2[3 * t + 1] = make_float2(c0.z, c1.x);
    o2[3 * t + 2] = make_float2(c1.y, c1.z);
}

extern "C" void kernel_launch(void* const* d_in, const int* in_sizes, int n_in,
                              void* d_out, int out_size, void* d_ws, size_t ws_size,
                              hipStream_t stream) {
    const float* x = (const float*)d_in[0];   // (NPTS, 2) fp32
    const float* p = (const float*)d_in[1];   // (700,)   fp32
    float* out = (float*)d_out;               // (NPTS, 3) fp32
    (void)d_ws; (void)ws_size;

    vg_fused<<<NTHREADS / 256, 256, 0, stream>>>(x, p, out);
}